// Round 10
// baseline (408.750 us; speedup 1.0000x reference)
//
#include <hip/hip_runtime.h>

#define N_NODES 50000
#define N_EDGES 800000
#define H 64
#define NPB 64            // nodes per bucket (receiver >> 6)
#define NBKT 782          // ceil(50000/64)
#define CAP 2048          // max edges per bucket (Poisson(1024); overflow P ~ 0)

typedef float floatx4 __attribute__((ext_vector_type(4)));

__device__ __forceinline__ float readlane_f(float x, int i) {
    return __int_as_float(__builtin_amdgcn_readlane(__float_as_int(x), i));
}
__device__ __forceinline__ unsigned bf16rne(float x) {
    unsigned u = __float_as_uint(x);
    return (u + 0x7FFFu + ((u >> 16) & 1u)) >> 16;
}
__device__ __forceinline__ float bf16lo(unsigned u) { return __uint_as_float(u << 16); }
__device__ __forceinline__ float bf16hi(unsigned u) { return __uint_as_float(u & 0xFFFF0000u); }

// ---- Stage 1: binned copy. Sequential E read; bf16 rows appended to per-bucket
// streams (782 concurrent sequential 128B write streams). 8 threads per row.
__global__ __launch_bounds__(256) void bcopy_kernel(
    const float* __restrict__ E, const int* __restrict__ recv,
    unsigned* __restrict__ cursor, unsigned short* __restrict__ ebNode,
    unsigned* __restrict__ Es)
{
    int t = blockIdx.x * 256 + threadIdx.x;     // < N_EDGES*8 exactly
    int edge = t >> 3;
    int c = t & 7;
    const int lane = threadIdx.x & 63;

    int r = recv[edge];                          // 8 threads read same value (broadcast)
    int b = r >> 6;

    unsigned pos = 0;
    if ((lane & 7) == 0) {
        pos = atomicAdd(&cursor[b], 1u);
        if (pos < CAP) ebNode[(size_t)b * CAP + pos] = (unsigned short)(r & 63);
    }
    pos = __shfl(pos, lane & 56);                // broadcast from leader of 8-lane group
    if (pos >= CAP) return;                      // never in practice

    const floatx4* E4 = reinterpret_cast<const floatx4*>(E);
    floatx4 a = __builtin_nontemporal_load(E4 + (size_t)edge * 16 + c * 2);
    floatx4 d = __builtin_nontemporal_load(E4 + (size_t)edge * 16 + c * 2 + 1);
    uint4 o;
    o.x = bf16rne(a.x) | (bf16rne(a.y) << 16);
    o.y = bf16rne(a.z) | (bf16rne(a.w) << 16);
    o.z = bf16rne(d.x) | (bf16rne(d.y) << 16);
    o.w = bf16rne(d.z) | (bf16rne(d.w) << 16);
    size_t row = (size_t)b * CAP + pos;
    reinterpret_cast<uint4*>(Es)[row * 8 + c] = o;
}

// ---- Stage 2: per-bucket segmented mean + MLP. One block per bucket.
// LDS: per-node hist -> wave shfl-scan -> list fill; then 16 waves x 4 nodes:
// gather 8 rows/wave-load from the L2/L3-resident bucket, reduce, MLP, store.
__global__ __launch_bounds__(1024, 8) void pass2_kernel(
    const unsigned* __restrict__ Es, const unsigned short* __restrict__ ebNode,
    const unsigned* __restrict__ cursor, const float* __restrict__ v,
    const float* __restrict__ W0, const float* __restrict__ b0,
    const float* __restrict__ W1, const float* __restrict__ b1,
    const float* __restrict__ W2, const float* __restrict__ b2,
    float* __restrict__ out)
{
    __shared__ float sW0[128 * 64];
    __shared__ float sW1[64 * 64];
    __shared__ float sW2[64 * 64];
    __shared__ float sB[3 * 64];
    __shared__ int cntL[NPB];
    __shared__ int startL[NPB];
    __shared__ int curL[NPB];
    __shared__ unsigned short list[CAP];

    const int tid = threadIdx.x;
    const int b = blockIdx.x;

    for (int i = tid; i < 128 * 64; i += 1024) sW0[i] = W0[i];
    for (int i = tid; i < 64 * 64; i += 1024) sW1[i] = W1[i];
    for (int i = tid; i < 64 * 64; i += 1024) sW2[i] = W2[i];
    if (tid < 192) {
        sB[tid] = (tid < 64) ? b0[tid] : (tid < 128) ? b1[tid - 64] : b2[tid - 128];
    }
    if (tid < NPB) cntL[tid] = 0;
    __syncthreads();

    int cb = (int)cursor[b];
    if (cb > CAP) cb = CAP;

    // per-node histogram within the bucket
    for (int i = tid; i < cb; i += 1024)
        atomicAdd(&cntL[ebNode[(size_t)b * CAP + i]], 1);
    __syncthreads();

    // exclusive scan of 64 counts by the first wave
    if (tid < 64) {
        int val = cntL[tid];
        int inc = val;
        #pragma unroll
        for (int off = 1; off < 64; off <<= 1) {
            int src = tid - off;
            int o = __shfl(inc, src < 0 ? 0 : src);
            if (tid >= off) inc += o;
        }
        startL[tid] = inc - val;
        curL[tid] = inc - val;
    }
    __syncthreads();

    // fill per-node edge lists
    for (int i = tid; i < cb; i += 1024) {
        int ln = ebNode[(size_t)b * CAP + i];
        int p = atomicAdd(&curL[ln], 1);
        list[p] = (unsigned short)i;
    }
    __syncthreads();

    const int lane = tid & 63;
    const int wid = tid >> 6;
    const int rg = lane >> 3;    // row-group 0..7
    const int ck = lane & 7;     // 16B chunk 0..7
    const uint4* Es4 = reinterpret_cast<const uint4*>(Es);
    const size_t bo = (size_t)b * CAP;

    float xa[4], xv[4];
    #pragma unroll
    for (int k = 0; k < 4; ++k) {
        int ln = wid * 4 + k;               // wave-uniform
        int n = b * NPB + ln;
        xa[k] = 0.0f; xv[k] = 0.0f;
        if (n < N_NODES) {
            xv[k] = v[(size_t)n * H + lane];
            int s0 = startL[ln];
            int c0 = cntL[ln];

            float f0 = 0.f, f1 = 0.f, f2 = 0.f, f3 = 0.f;
            float f4 = 0.f, f5 = 0.f, f6 = 0.f, f7 = 0.f;
            for (int p = 0; p < c0; p += 8) {
                int rr = p + rg;
                if (rr < c0) {
                    int idx = list[s0 + rr];
                    uint4 q = Es4[(bo + (size_t)idx) * 8 + ck];
                    f0 += bf16lo(q.x); f1 += bf16hi(q.x);
                    f2 += bf16lo(q.y); f3 += bf16hi(q.y);
                    f4 += bf16lo(q.z); f5 += bf16hi(q.z);
                    f6 += bf16lo(q.w); f7 += bf16hi(q.w);
                }
            }
            // reduce across 8 row-groups (lane bits 3,4,5)
            f0 += __shfl_xor(f0, 8);  f1 += __shfl_xor(f1, 8);
            f2 += __shfl_xor(f2, 8);  f3 += __shfl_xor(f3, 8);
            f4 += __shfl_xor(f4, 8);  f5 += __shfl_xor(f5, 8);
            f6 += __shfl_xor(f6, 8);  f7 += __shfl_xor(f7, 8);
            f0 += __shfl_xor(f0, 16); f1 += __shfl_xor(f1, 16);
            f2 += __shfl_xor(f2, 16); f3 += __shfl_xor(f3, 16);
            f4 += __shfl_xor(f4, 16); f5 += __shfl_xor(f5, 16);
            f6 += __shfl_xor(f6, 16); f7 += __shfl_xor(f7, 16);
            f0 += __shfl_xor(f0, 32); f1 += __shfl_xor(f1, 32);
            f2 += __shfl_xor(f2, 32); f3 += __shfl_xor(f3, 32);
            f4 += __shfl_xor(f4, 32); f5 += __shfl_xor(f5, 32);
            f6 += __shfl_xor(f6, 32); f7 += __shfl_xor(f7, 32);

            // redistribute: feature f=lane is slot f&7 of source lane f>>3
            int src = lane >> 3;
            float t0 = __shfl(f0, src), t1 = __shfl(f1, src);
            float t2 = __shfl(f2, src), t3 = __shfl(f3, src);
            float t4 = __shfl(f4, src), t5 = __shfl(f5, src);
            float t6 = __shfl(f6, src), t7 = __shfl(f7, src);
            float a01 = (lane & 1) ? t1 : t0;
            float a23 = (lane & 1) ? t3 : t2;
            float a45 = (lane & 1) ? t5 : t4;
            float a67 = (lane & 1) ? t7 : t6;
            float b03 = (lane & 2) ? a23 : a01;
            float b47 = (lane & 2) ? a67 : a45;
            float sel = (lane & 4) ? b47 : b03;

            xa[k] = (c0 > 0) ? sel * (1.0f / (float)c0) : 0.0f;
        }
    }

    // ---- MLP: 1 LDS weight read per K-step amortized over 4 nodes ----
    float acc[4];
    #pragma unroll
    for (int k = 0; k < 4; ++k) acc[k] = sB[lane];
    #pragma unroll 8
    for (int i = 0; i < 64; ++i) {
        float w = sW0[i * 64 + lane];
        #pragma unroll
        for (int k = 0; k < 4; ++k) acc[k] = fmaf(readlane_f(xa[k], i), w, acc[k]);
    }
    #pragma unroll 8
    for (int i = 0; i < 64; ++i) {
        float w = sW0[(64 + i) * 64 + lane];
        #pragma unroll
        for (int k = 0; k < 4; ++k) acc[k] = fmaf(readlane_f(xv[k], i), w, acc[k]);
    }
    float y[4];
    #pragma unroll
    for (int k = 0; k < 4; ++k) y[k] = fmaxf(acc[k], 0.0f);

    #pragma unroll
    for (int k = 0; k < 4; ++k) acc[k] = sB[64 + lane];
    #pragma unroll 8
    for (int i = 0; i < 64; ++i) {
        float w = sW1[i * 64 + lane];
        #pragma unroll
        for (int k = 0; k < 4; ++k) acc[k] = fmaf(readlane_f(y[k], i), w, acc[k]);
    }
    float z[4];
    #pragma unroll
    for (int k = 0; k < 4; ++k) z[k] = fmaxf(acc[k], 0.0f);

    #pragma unroll
    for (int k = 0; k < 4; ++k) acc[k] = sB[128 + lane];
    #pragma unroll 8
    for (int i = 0; i < 64; ++i) {
        float w = sW2[i * 64 + lane];
        #pragma unroll
        for (int k = 0; k < 4; ++k) acc[k] = fmaf(readlane_f(z[k], i), w, acc[k]);
    }

    #pragma unroll
    for (int k = 0; k < 4; ++k) {
        int n = b * NPB + wid * 4 + k;
        if (n < N_NODES) out[(size_t)n * H + lane] = acc[k];
    }
}

extern "C" void kernel_launch(void* const* d_in, const int* in_sizes, int n_in,
                              void* d_out, int out_size, void* d_ws, size_t ws_size,
                              hipStream_t stream)
{
    const float* v  = (const float*)d_in[0];
    const int*   ei = (const int*)d_in[1];     // [2, 800000]; row 1 = receiver
    const float* e  = (const float*)d_in[2];
    const float* W0 = (const float*)d_in[3];
    const float* b0 = (const float*)d_in[4];
    const float* W1 = (const float*)d_in[5];
    const float* b1 = (const float*)d_in[6];
    const float* W2 = (const float*)d_in[7];
    const float* b2 = (const float*)d_in[8];
    float* out = (float*)d_out;

    // workspace layout (u32 units)
    unsigned* W = (unsigned*)d_ws;
    unsigned*       cursor = W;                                   // [0,1024)
    unsigned short* ebNode = (unsigned short*)(W + 1024);         // 782*2048 u16 = 800768 u32
    unsigned*       Es     = W + 1024 + 800768;                   // 782*2048 rows * 32 u32 (~205 MB)
    const int* recv = ei + N_EDGES;

    (void)hipMemsetAsync(cursor, 0, 1024 * sizeof(unsigned), stream);

    bcopy_kernel<<<(N_EDGES * 8) / 256, 256, 0, stream>>>(e, recv, cursor, ebNode, Es);
    pass2_kernel<<<NBKT, 1024, 0, stream>>>(
        Es, ebNode, cursor, v, W0, b0, W1, b1, W2, b2, out);
}

// Round 11
// 204.907 us; speedup vs baseline: 1.9948x; 1.9948x over previous
//
#include <hip/hip_runtime.h>

#define N_NODES 50000
#define N_EDGES 800000
#define H 64
#define NBLK 196        // ceil(50000/256)
#define TOTAL_WAVES 8192
#define NPWMAX 7        // ceil(50000/8192)

__device__ __forceinline__ float readlane_f(float x, int i) {
    return __int_as_float(__builtin_amdgcn_readlane(__float_as_int(x), i));
}

// ---- Stage 1: histogram of receiver counts ----
__global__ __launch_bounds__(256) void hist_kernel(
    const int* __restrict__ recv, unsigned* __restrict__ counts)
{
    int i = blockIdx.x * 256 + threadIdx.x;
    if (i < N_EDGES / 4) {
        int4 r = reinterpret_cast<const int4*>(recv)[i];
        atomicAdd(&counts[r.x], 1u);
        atomicAdd(&counts[r.y], 1u);
        atomicAdd(&counts[r.z], 1u);
        atomicAdd(&counts[r.w], 1u);
    }
}

// ---- Stage 2a: per-block reduce ----
__global__ __launch_bounds__(256) void scanA_kernel(
    const unsigned* __restrict__ counts, unsigned* __restrict__ blockSums)
{
    __shared__ unsigned red[256];
    int i = blockIdx.x * 256 + threadIdx.x;
    unsigned s = (i < N_NODES) ? counts[i] : 0u;
    red[threadIdx.x] = s;
    __syncthreads();
    for (int off = 128; off > 0; off >>= 1) {
        if (threadIdx.x < off) red[threadIdx.x] += red[threadIdx.x + off];
        __syncthreads();
    }
    if (threadIdx.x == 0) blockSums[blockIdx.x] = red[0];
}

// ---- Stage 2b: per-block scan (derives own prefix) ----
__global__ __launch_bounds__(256) void scanC_kernel(
    const unsigned* __restrict__ counts, const unsigned* __restrict__ blockSums,
    unsigned* __restrict__ offsets, unsigned* __restrict__ cursor)
{
    __shared__ unsigned sh[256];
    const int t = threadIdx.x;

    sh[t] = (t < blockIdx.x && t < NBLK) ? blockSums[t] : 0u;
    __syncthreads();
    for (int off = 128; off > 0; off >>= 1) {
        if (t < off) sh[t] += sh[t + off];
        __syncthreads();
    }
    unsigned blockPrefix = sh[0];
    __syncthreads();

    int i = blockIdx.x * 256 + t;
    unsigned c = (i < N_NODES) ? counts[i] : 0u;
    sh[t] = c;
    __syncthreads();
    for (int off = 1; off < 256; off <<= 1) {
        unsigned vv = (t >= off) ? sh[t - off] : 0u;
        __syncthreads();
        sh[t] += vv;
        __syncthreads();
    }
    unsigned ex = sh[t] - c + blockPrefix;
    if (i < N_NODES) { offsets[i] = ex; cursor[i] = ex; }
    if (i == 0) offsets[N_NODES] = N_EDGES;
}

// ---- Stage 3: scatter edge ids into receiver buckets ----
__global__ __launch_bounds__(256) void bucket_kernel(
    const int* __restrict__ recv, unsigned* __restrict__ cursor,
    unsigned* __restrict__ perm)
{
    int i = blockIdx.x * 256 + threadIdx.x;
    if (i < N_EDGES / 4) {
        int4 r = reinterpret_cast<const int4*>(recv)[i];
        unsigned p0 = atomicAdd(&cursor[r.x], 1u);
        unsigned p1 = atomicAdd(&cursor[r.y], 1u);
        unsigned p2 = atomicAdd(&cursor[r.z], 1u);
        unsigned p3 = atomicAdd(&cursor[r.w], 1u);
        perm[p0] = (unsigned)(i * 4 + 0);
        perm[p1] = (unsigned)(i * 4 + 1);
        perm[p2] = (unsigned)(i * 4 + 2);
        perm[p3] = (unsigned)(i * 4 + 3);
    }
}

// ---- Stage 4: fused gather-mean + amortized MLP ----
// 512 blocks x 1024 thr = 8192 waves, 2 blocks/CU; wave g: nodes {g + j*8192}.
// Gather: one coalesced perm load grabs 64 indices; readlane -> SGPR base;
// 8 independent E-row loads in flight per batch (scalar addressing).
// MLP: one ds_read_b32 weight per K-step amortized over 7 nodes.
__global__ __launch_bounds__(1024, 8) void gather_mlp_kernel(
    const float* __restrict__ E, const unsigned* __restrict__ offsets,
    const unsigned* __restrict__ perm, const float* __restrict__ v,
    const float* __restrict__ W0, const float* __restrict__ b0,
    const float* __restrict__ W1, const float* __restrict__ b1,
    const float* __restrict__ W2, const float* __restrict__ b2,
    float* __restrict__ out)
{
    __shared__ float sW0[128 * 64];
    __shared__ float sW1[64 * 64];
    __shared__ float sW2[64 * 64];
    __shared__ float sB[3 * 64];

    for (int i = threadIdx.x; i < 128 * 64; i += 1024) sW0[i] = W0[i];
    for (int i = threadIdx.x; i < 64 * 64; i += 1024) sW1[i] = W1[i];
    for (int i = threadIdx.x; i < 64 * 64; i += 1024) sW2[i] = W2[i];
    if (threadIdx.x < 192) {
        sB[threadIdx.x] = (threadIdx.x < 64)   ? b0[threadIdx.x]
                        : (threadIdx.x < 128)  ? b1[threadIdx.x - 64]
                                               : b2[threadIdx.x - 128];
    }
    __syncthreads();

    const int lane = threadIdx.x & 63;
    int g = (blockIdx.x * 1024 + threadIdx.x) >> 6;
    g = __builtin_amdgcn_readfirstlane(g);

    float xa[NPWMAX], xv[NPWMAX];
    #pragma unroll
    for (int j = 0; j < NPWMAX; ++j) {
        int n = g + j * TOTAL_WAVES;
        xa[j] = 0.0f; xv[j] = 0.0f;
        if (n < N_NODES) {
            xv[j] = v[(size_t)n * H + lane];
            int beg = __builtin_amdgcn_readfirstlane((int)offsets[n]);
            int end = __builtin_amdgcn_readfirstlane((int)offsets[n + 1]);
            int cnt = end - beg;

            float s = 0.0f;
            for (int base = beg; base < end; base += 64) {
                int nb = end - base; if (nb > 64) nb = 64;
                // one coalesced load: lane l holds index of row base+l
                int idxs = (lane < nb) ? (int)perm[base + lane] : 0;

                int p = 0;
                for (; p + 8 <= nb; p += 8) {
                    // 8 independent row loads, SGPR-based addressing
                    int i0 = __builtin_amdgcn_readlane(idxs, p + 0);
                    int i1 = __builtin_amdgcn_readlane(idxs, p + 1);
                    int i2 = __builtin_amdgcn_readlane(idxs, p + 2);
                    int i3 = __builtin_amdgcn_readlane(idxs, p + 3);
                    int i4 = __builtin_amdgcn_readlane(idxs, p + 4);
                    int i5 = __builtin_amdgcn_readlane(idxs, p + 5);
                    int i6 = __builtin_amdgcn_readlane(idxs, p + 6);
                    int i7 = __builtin_amdgcn_readlane(idxs, p + 7);
                    float t0 = E[(size_t)i0 * H + lane];
                    float t1 = E[(size_t)i1 * H + lane];
                    float t2 = E[(size_t)i2 * H + lane];
                    float t3 = E[(size_t)i3 * H + lane];
                    float t4 = E[(size_t)i4 * H + lane];
                    float t5 = E[(size_t)i5 * H + lane];
                    float t6 = E[(size_t)i6 * H + lane];
                    float t7 = E[(size_t)i7 * H + lane];
                    s += ((t0 + t1) + (t2 + t3)) + ((t4 + t5) + (t6 + t7));
                }
                for (; p < nb; ++p) {
                    int iq = __builtin_amdgcn_readlane(idxs, p);
                    s += E[(size_t)iq * H + lane];
                }
            }
            float invc = (cnt > 0) ? 1.0f / (float)cnt : 0.0f;
            xa[j] = s * invc;
        }
    }

    // ---- MLP: 1 LDS weight read per K-step, shared by 7 nodes ----
    float acc[NPWMAX];
    #pragma unroll
    for (int j = 0; j < NPWMAX; ++j) acc[j] = sB[lane];
    #pragma unroll 8
    for (int i = 0; i < 64; ++i) {
        float w = sW0[i * 64 + lane];
        #pragma unroll
        for (int j = 0; j < NPWMAX; ++j) acc[j] = fmaf(readlane_f(xa[j], i), w, acc[j]);
    }
    #pragma unroll 8
    for (int i = 0; i < 64; ++i) {
        float w = sW0[(64 + i) * 64 + lane];
        #pragma unroll
        for (int j = 0; j < NPWMAX; ++j) acc[j] = fmaf(readlane_f(xv[j], i), w, acc[j]);
    }
    float y[NPWMAX];
    #pragma unroll
    for (int j = 0; j < NPWMAX; ++j) y[j] = fmaxf(acc[j], 0.0f);

    #pragma unroll
    for (int j = 0; j < NPWMAX; ++j) acc[j] = sB[64 + lane];
    #pragma unroll 8
    for (int i = 0; i < 64; ++i) {
        float w = sW1[i * 64 + lane];
        #pragma unroll
        for (int j = 0; j < NPWMAX; ++j) acc[j] = fmaf(readlane_f(y[j], i), w, acc[j]);
    }
    float z[NPWMAX];
    #pragma unroll
    for (int j = 0; j < NPWMAX; ++j) z[j] = fmaxf(acc[j], 0.0f);

    #pragma unroll
    for (int j = 0; j < NPWMAX; ++j) acc[j] = sB[128 + lane];
    #pragma unroll 8
    for (int i = 0; i < 64; ++i) {
        float w = sW2[i * 64 + lane];
        #pragma unroll
        for (int j = 0; j < NPWMAX; ++j) acc[j] = fmaf(readlane_f(z[j], i), w, acc[j]);
    }

    #pragma unroll
    for (int j = 0; j < NPWMAX; ++j) {
        int n = g + j * TOTAL_WAVES;
        if (n < N_NODES) out[(size_t)n * H + lane] = acc[j];
    }
}

extern "C" void kernel_launch(void* const* d_in, const int* in_sizes, int n_in,
                              void* d_out, int out_size, void* d_ws, size_t ws_size,
                              hipStream_t stream)
{
    const float* v  = (const float*)d_in[0];
    const int*   ei = (const int*)d_in[1];     // [2, 800000]; row 1 = receiver
    const float* e  = (const float*)d_in[2];
    const float* W0 = (const float*)d_in[3];
    const float* b0 = (const float*)d_in[4];
    const float* W1 = (const float*)d_in[5];
    const float* b1 = (const float*)d_in[6];
    const float* W2 = (const float*)d_in[7];
    const float* b2 = (const float*)d_in[8];
    float* out = (float*)d_out;

    // workspace layout (u32 elements)
    unsigned* W = (unsigned*)d_ws;
    unsigned* counts    = W;                  // [0, 50176)
    unsigned* offsets   = W + 50176;          // 50001 (+pad)
    unsigned* cursor    = W + 100352;         // 50000 (+pad)
    unsigned* blockSums = W + 150528;         // 196 (+pad)
    unsigned* perm      = W + 150784;         // 800000
    const int* recv = ei + N_EDGES;

    (void)hipMemsetAsync(counts, 0, 50176 * sizeof(unsigned), stream);

    hist_kernel<<<(N_EDGES / 4 + 255) / 256, 256, 0, stream>>>(recv, counts);
    scanA_kernel<<<NBLK, 256, 0, stream>>>(counts, blockSums);
    scanC_kernel<<<NBLK, 256, 0, stream>>>(counts, blockSums, offsets, cursor);
    bucket_kernel<<<(N_EDGES / 4 + 255) / 256, 256, 0, stream>>>(recv, cursor, perm);
    gather_mlp_kernel<<<512, 1024, 0, stream>>>(
        e, offsets, perm, v, W0, b0, W1, b1, W2, b2, out);
}

// Round 12
// 204.082 us; speedup vs baseline: 2.0029x; 1.0040x over previous
//
#include <hip/hip_runtime.h>

#define N_NODES 50000
#define N_EDGES 800000
#define H 64
#define NBLK 196        // ceil(50000/256)
#define TOTAL_WAVES 8192
#define NPWMAX 7        // ceil(50000/8192)

typedef float floatx4 __attribute__((ext_vector_type(4)));

__device__ __forceinline__ float readlane_f(float x, int i) {
    return __int_as_float(__builtin_amdgcn_readlane(__float_as_int(x), i));
}
__device__ __forceinline__ unsigned bf16rne(float x) {
    unsigned u = __float_as_uint(x);
    return (u + 0x7FFFu + ((u >> 16) & 1u)) >> 16;
}
__device__ __forceinline__ float bf16lo(unsigned u) { return __uint_as_float(u << 16); }
__device__ __forceinline__ float bf16hi(unsigned u) { return __uint_as_float(u & 0xFFFF0000u); }

// ---- Stage 1: histogram of receiver counts ----
__global__ __launch_bounds__(256) void hist_kernel(
    const int* __restrict__ recv, unsigned* __restrict__ counts)
{
    int i = blockIdx.x * 256 + threadIdx.x;
    if (i < N_EDGES / 4) {
        int4 r = reinterpret_cast<const int4*>(recv)[i];
        atomicAdd(&counts[r.x], 1u);
        atomicAdd(&counts[r.y], 1u);
        atomicAdd(&counts[r.z], 1u);
        atomicAdd(&counts[r.w], 1u);
    }
}

// ---- Stage 2a: per-block reduce ----
__global__ __launch_bounds__(256) void scanA_kernel(
    const unsigned* __restrict__ counts, unsigned* __restrict__ blockSums)
{
    __shared__ unsigned red[256];
    int i = blockIdx.x * 256 + threadIdx.x;
    unsigned s = (i < N_NODES) ? counts[i] : 0u;
    red[threadIdx.x] = s;
    __syncthreads();
    for (int off = 128; off > 0; off >>= 1) {
        if (threadIdx.x < off) red[threadIdx.x] += red[threadIdx.x + off];
        __syncthreads();
    }
    if (threadIdx.x == 0) blockSums[blockIdx.x] = red[0];
}

// ---- Stage 2b: per-block scan (derives own prefix) ----
__global__ __launch_bounds__(256) void scanC_kernel(
    const unsigned* __restrict__ counts, const unsigned* __restrict__ blockSums,
    unsigned* __restrict__ offsets, unsigned* __restrict__ cursor)
{
    __shared__ unsigned sh[256];
    const int t = threadIdx.x;

    sh[t] = (t < blockIdx.x && t < NBLK) ? blockSums[t] : 0u;
    __syncthreads();
    for (int off = 128; off > 0; off >>= 1) {
        if (t < off) sh[t] += sh[t + off];
        __syncthreads();
    }
    unsigned blockPrefix = sh[0];
    __syncthreads();

    int i = blockIdx.x * 256 + t;
    unsigned c = (i < N_NODES) ? counts[i] : 0u;
    sh[t] = c;
    __syncthreads();
    for (int off = 1; off < 256; off <<= 1) {
        unsigned vv = (t >= off) ? sh[t - off] : 0u;
        __syncthreads();
        sh[t] += vv;
        __syncthreads();
    }
    unsigned ex = sh[t] - c + blockPrefix;
    if (i < N_NODES) { offsets[i] = ex; cursor[i] = ex; }
    if (i == 0) offsets[N_NODES] = N_EDGES;
}

// ---- Stage 3: fused position-claim + f32->bf16 permuted copy ----
// 8 threads per edge row. Leader lane claims sorted slot via atomicAdd on the
// node cursor (50K counters, ~16 hits each); pos broadcast by shfl; each thread
// converts 8 feats to bf16 and writes one 16B chunk of the 128B sorted row.
__global__ __launch_bounds__(256) void bcopy_kernel(
    const float* __restrict__ E, const int* __restrict__ recv,
    unsigned* __restrict__ cursor, unsigned* __restrict__ Es)
{
    int t = blockIdx.x * 256 + threadIdx.x;     // < N_EDGES*8 exactly
    int edge = t >> 3;
    int c = t & 7;
    const int lane = threadIdx.x & 63;

    int r = recv[edge];
    unsigned pos = 0;
    if ((lane & 7) == 0) pos = atomicAdd(&cursor[r], 1u);
    pos = __shfl(pos, lane & 56);               // broadcast from 8-lane-group leader

    const floatx4* E4 = reinterpret_cast<const floatx4*>(E);
    floatx4 a = __builtin_nontemporal_load(E4 + (size_t)edge * 16 + c * 2);
    floatx4 d = __builtin_nontemporal_load(E4 + (size_t)edge * 16 + c * 2 + 1);
    uint4 o;
    o.x = bf16rne(a.x) | (bf16rne(a.y) << 16);
    o.y = bf16rne(a.z) | (bf16rne(a.w) << 16);
    o.z = bf16rne(d.x) | (bf16rne(d.y) << 16);
    o.w = bf16rne(d.z) | (bf16rne(d.w) << 16);
    reinterpret_cast<uint4*>(Es)[(size_t)pos * 8 + c] = o;
}

// ---- Stage 4: fused segmented-mean (contiguous bf16 rows) + amortized MLP ----
// 512 blocks x 1024 thr = 8192 waves; wave g handles nodes {g + j*8192}.
// Mean: 8 rows per wave-load (lane l: row p+(l>>3), chunk c=l&7, 16B=8 bf16).
// MLP: one ds_read_b32 weight per K-step amortized over 7 nodes.
__global__ __launch_bounds__(1024, 8) void gather_mlp_kernel(
    const unsigned* __restrict__ Es, const unsigned* __restrict__ offsets,
    const float* __restrict__ v,
    const float* __restrict__ W0, const float* __restrict__ b0,
    const float* __restrict__ W1, const float* __restrict__ b1,
    const float* __restrict__ W2, const float* __restrict__ b2,
    float* __restrict__ out)
{
    __shared__ float sW0[128 * 64];
    __shared__ float sW1[64 * 64];
    __shared__ float sW2[64 * 64];
    __shared__ float sB[3 * 64];

    for (int i = threadIdx.x; i < 128 * 64; i += 1024) sW0[i] = W0[i];
    for (int i = threadIdx.x; i < 64 * 64; i += 1024) sW1[i] = W1[i];
    for (int i = threadIdx.x; i < 64 * 64; i += 1024) sW2[i] = W2[i];
    if (threadIdx.x < 192) {
        sB[threadIdx.x] = (threadIdx.x < 64)   ? b0[threadIdx.x]
                        : (threadIdx.x < 128)  ? b1[threadIdx.x - 64]
                                               : b2[threadIdx.x - 128];
    }
    __syncthreads();

    const int lane = threadIdx.x & 63;
    int g = (blockIdx.x * 1024 + threadIdx.x) >> 6;
    g = __builtin_amdgcn_readfirstlane(g);

    const int rg = lane >> 3;     // row-group 0..7
    const int ck = lane & 7;      // 16B chunk 0..7
    const uint4* Es4 = reinterpret_cast<const uint4*>(Es);

    float xa[NPWMAX], xv[NPWMAX];
    #pragma unroll
    for (int j = 0; j < NPWMAX; ++j) {
        int n = g + j * TOTAL_WAVES;
        xa[j] = 0.0f; xv[j] = 0.0f;
        if (n < N_NODES) {
            xv[j] = v[(size_t)n * H + lane];
            int beg = __builtin_amdgcn_readfirstlane((int)offsets[n]);
            int end = __builtin_amdgcn_readfirstlane((int)offsets[n + 1]);
            int cnt = end - beg;

            float f0 = 0.f, f1 = 0.f, f2 = 0.f, f3 = 0.f;
            float f4 = 0.f, f5 = 0.f, f6 = 0.f, f7 = 0.f;
            for (int p = beg; p < end; p += 8) {
                int r = p + rg;
                if (r < end) {
                    uint4 q = Es4[(size_t)r * 8 + ck];
                    f0 += bf16lo(q.x); f1 += bf16hi(q.x);
                    f2 += bf16lo(q.y); f3 += bf16hi(q.y);
                    f4 += bf16lo(q.z); f5 += bf16hi(q.z);
                    f6 += bf16lo(q.w); f7 += bf16hi(q.w);
                }
            }
            // reduce across 8 row-groups (lane bits 3,4,5)
            f0 += __shfl_xor(f0, 8);  f1 += __shfl_xor(f1, 8);
            f2 += __shfl_xor(f2, 8);  f3 += __shfl_xor(f3, 8);
            f4 += __shfl_xor(f4, 8);  f5 += __shfl_xor(f5, 8);
            f6 += __shfl_xor(f6, 8);  f7 += __shfl_xor(f7, 8);
            f0 += __shfl_xor(f0, 16); f1 += __shfl_xor(f1, 16);
            f2 += __shfl_xor(f2, 16); f3 += __shfl_xor(f3, 16);
            f4 += __shfl_xor(f4, 16); f5 += __shfl_xor(f5, 16);
            f6 += __shfl_xor(f6, 16); f7 += __shfl_xor(f7, 16);
            f0 += __shfl_xor(f0, 32); f1 += __shfl_xor(f1, 32);
            f2 += __shfl_xor(f2, 32); f3 += __shfl_xor(f3, 32);
            f4 += __shfl_xor(f4, 32); f5 += __shfl_xor(f5, 32);
            f6 += __shfl_xor(f6, 32); f7 += __shfl_xor(f7, 32);

            // redistribute: feature f=lane is slot f&7 of source lane f>>3
            int src = lane >> 3;
            float t0 = __shfl(f0, src), t1 = __shfl(f1, src);
            float t2 = __shfl(f2, src), t3 = __shfl(f3, src);
            float t4 = __shfl(f4, src), t5 = __shfl(f5, src);
            float t6 = __shfl(f6, src), t7 = __shfl(f7, src);
            float a01 = (lane & 1) ? t1 : t0;
            float a23 = (lane & 1) ? t3 : t2;
            float a45 = (lane & 1) ? t5 : t4;
            float a67 = (lane & 1) ? t7 : t6;
            float b03 = (lane & 2) ? a23 : a01;
            float b47 = (lane & 2) ? a67 : a45;
            float sel = (lane & 4) ? b47 : b03;

            float invc = (cnt > 0) ? 1.0f / (float)cnt : 0.0f;
            xa[j] = sel * invc;
        }
    }

    // ---- MLP: 1 LDS weight read per K-step, shared by 7 nodes ----
    float acc[NPWMAX];
    #pragma unroll
    for (int j = 0; j < NPWMAX; ++j) acc[j] = sB[lane];
    #pragma unroll 8
    for (int i = 0; i < 64; ++i) {
        float w = sW0[i * 64 + lane];
        #pragma unroll
        for (int j = 0; j < NPWMAX; ++j) acc[j] = fmaf(readlane_f(xa[j], i), w, acc[j]);
    }
    #pragma unroll 8
    for (int i = 0; i < 64; ++i) {
        float w = sW0[(64 + i) * 64 + lane];
        #pragma unroll
        for (int j = 0; j < NPWMAX; ++j) acc[j] = fmaf(readlane_f(xv[j], i), w, acc[j]);
    }
    float y[NPWMAX];
    #pragma unroll
    for (int j = 0; j < NPWMAX; ++j) y[j] = fmaxf(acc[j], 0.0f);

    #pragma unroll
    for (int j = 0; j < NPWMAX; ++j) acc[j] = sB[64 + lane];
    #pragma unroll 8
    for (int i = 0; i < 64; ++i) {
        float w = sW1[i * 64 + lane];
        #pragma unroll
        for (int j = 0; j < NPWMAX; ++j) acc[j] = fmaf(readlane_f(y[j], i), w, acc[j]);
    }
    float z[NPWMAX];
    #pragma unroll
    for (int j = 0; j < NPWMAX; ++j) z[j] = fmaxf(acc[j], 0.0f);

    #pragma unroll
    for (int j = 0; j < NPWMAX; ++j) acc[j] = sB[128 + lane];
    #pragma unroll 8
    for (int i = 0; i < 64; ++i) {
        float w = sW2[i * 64 + lane];
        #pragma unroll
        for (int j = 0; j < NPWMAX; ++j) acc[j] = fmaf(readlane_f(z[j], i), w, acc[j]);
    }

    #pragma unroll
    for (int j = 0; j < NPWMAX; ++j) {
        int n = g + j * TOTAL_WAVES;
        if (n < N_NODES) out[(size_t)n * H + lane] = acc[j];
    }
}

extern "C" void kernel_launch(void* const* d_in, const int* in_sizes, int n_in,
                              void* d_out, int out_size, void* d_ws, size_t ws_size,
                              hipStream_t stream)
{
    const float* v  = (const float*)d_in[0];
    const int*   ei = (const int*)d_in[1];     // [2, 800000]; row 1 = receiver
    const float* e  = (const float*)d_in[2];
    const float* W0 = (const float*)d_in[3];
    const float* b0 = (const float*)d_in[4];
    const float* W1 = (const float*)d_in[5];
    const float* b1 = (const float*)d_in[6];
    const float* W2 = (const float*)d_in[7];
    const float* b2 = (const float*)d_in[8];
    float* out = (float*)d_out;

    // workspace layout (u32 elements)
    unsigned* W = (unsigned*)d_ws;
    unsigned* counts    = W;                    // [0, 50176)
    unsigned* offsets   = W + 50176;            // 50001 (+pad)
    unsigned* cursor    = W + 100352;           // 50000 (+pad)
    unsigned* blockSums = W + 150528;           // 196 (+pad)
    unsigned* Es        = W + 150784;           // 800000 rows * 32 u32 = 25.6M u32 (102.4 MB)
    const int* recv = ei + N_EDGES;

    (void)hipMemsetAsync(counts, 0, 50176 * sizeof(unsigned), stream);

    hist_kernel<<<(N_EDGES / 4 + 255) / 256, 256, 0, stream>>>(recv, counts);
    scanA_kernel<<<NBLK, 256, 0, stream>>>(counts, blockSums);
    scanC_kernel<<<NBLK, 256, 0, stream>>>(counts, blockSums, offsets, cursor);
    bcopy_kernel<<<(N_EDGES * 8) / 256, 256, 0, stream>>>(e, recv, cursor, Es);
    gather_mlp_kernel<<<512, 1024, 0, stream>>>(
        Es, offsets, v, W0, b0, W1, b1, W2, b2, out);
}

// Round 13
// 171.213 us; speedup vs baseline: 2.3874x; 1.1920x over previous
//
#include <hip/hip_runtime.h>

#define N_NODES 50000
#define N_EDGES 800000
#define H 64
#define NB 250          // coarse buckets (node / 200)
#define NPB 200         // nodes per bucket
#define NPH 100         // nodes per half-bucket (pass D block)
#define EPB 3200        // edges per pass-A/C block (250 * 3200 = 800000)
#define CAPD 2048       // max rows per half-bucket list (Poisson(1600), 11 sigma)
#define NPW 7

typedef float floatx4 __attribute__((ext_vector_type(4)));

__device__ __forceinline__ float readlane_f(float x, int i) {
    return __int_as_float(__builtin_amdgcn_readlane(__float_as_int(x), i));
}
__device__ __forceinline__ unsigned bf16rne(float x) {
    unsigned u = __float_as_uint(x);
    return (u + 0x7FFFu + ((u >> 16) & 1u)) >> 16;
}
__device__ __forceinline__ float bf16lo(unsigned u) { return __uint_as_float(u << 16); }
__device__ __forceinline__ float bf16hi(unsigned u) { return __uint_as_float(u & 0xFFFF0000u); }

// ---- Pass A: per-block bucket histogram (LDS atomics only) ----
__global__ __launch_bounds__(256) void histA_kernel(
    const int* __restrict__ recv, unsigned* __restrict__ histMatT)
{
    __shared__ unsigned h[NB];
    const int g = blockIdx.x;
    if (threadIdx.x < NB) h[threadIdx.x] = 0;
    __syncthreads();
    for (int i = threadIdx.x; i < EPB; i += 256)
        atomicAdd(&h[recv[g * EPB + i] / NPB], 1u);
    __syncthreads();
    if (threadIdx.x < NB) histMatT[threadIdx.x * NB + g] = h[threadIdx.x];
}

// ---- Pass B1: per-bucket exclusive scan over blocks ----
__global__ __launch_bounds__(256) void scanB1_kernel(
    const unsigned* __restrict__ histMatT, unsigned* __restrict__ offMatT,
    unsigned* __restrict__ bucketTotal)
{
    __shared__ unsigned sh[256];
    const int b = blockIdx.x;
    const int t = threadIdx.x;
    unsigned vals = (t < NB) ? histMatT[b * NB + t] : 0u;
    sh[t] = vals;
    __syncthreads();
    for (int off = 1; off < 256; off <<= 1) {
        unsigned vv = (t >= off) ? sh[t - off] : 0u;
        __syncthreads();
        sh[t] += vv;
        __syncthreads();
    }
    if (t < NB) offMatT[b * NB + t] = sh[t] - vals;   // exclusive prefix over blocks
    if (t == 255) bucketTotal[b] = sh[255];
}

// ---- Pass B2: exclusive scan of bucket totals ----
__global__ __launch_bounds__(256) void scanB2_kernel(
    const unsigned* __restrict__ bucketTotal, unsigned* __restrict__ bucketStart)
{
    __shared__ unsigned sh[256];
    const int t = threadIdx.x;
    unsigned vals = (t < NB) ? bucketTotal[t] : 0u;
    sh[t] = vals;
    __syncthreads();
    for (int off = 1; off < 256; off <<= 1) {
        unsigned vv = (t >= off) ? sh[t - off] : 0u;
        __syncthreads();
        sh[t] += vv;
        __syncthreads();
    }
    if (t < NB) bucketStart[t] = sh[t] - vals;
    if (t == 255) bucketStart[NB] = sh[255];
}

// ---- Pass C: contention-free scatter. LDS cursors from offset matrix;
// each block's same-bucket rows land contiguously (~1.6KB runs). ----
__global__ __launch_bounds__(1024) void scatterC_kernel(
    const float* __restrict__ E, const int* __restrict__ recv,
    const unsigned* __restrict__ offMatT, const unsigned* __restrict__ bucketStart,
    unsigned short* __restrict__ tags, unsigned* __restrict__ Es)
{
    __shared__ unsigned cur[NB];
    __shared__ unsigned posBuf[EPB];
    const int g = blockIdx.x;
    const int t = threadIdx.x;
    if (t < NB) cur[t] = bucketStart[t] + offMatT[t * NB + g];
    __syncthreads();

    // phase 1: claim positions + write node tags
    for (int i = t; i < EPB; i += 1024) {
        int r = recv[(size_t)g * EPB + i];
        int b = r / NPB;
        unsigned pos = atomicAdd(&cur[b], 1u);   // LDS atomic
        posBuf[i] = pos;
        tags[pos] = (unsigned short)(r % NPB);
    }
    __syncthreads();

    // phase 2: sequential E read, f32->bf16, write 16B chunk of 128B row
    const floatx4* E4 = reinterpret_cast<const floatx4*>(E);
    uint4* Es4 = reinterpret_cast<uint4*>(Es);
    #pragma unroll 5
    for (int it = 0; it < (EPB * 8) / 1024; ++it) {   // 25 iters
        int slot = it * 1024 + t;
        int row = slot >> 3;
        int c = slot & 7;
        unsigned pos = posBuf[row];
        size_t edge = (size_t)g * EPB + row;
        floatx4 a = __builtin_nontemporal_load(E4 + edge * 16 + c * 2);
        floatx4 d = __builtin_nontemporal_load(E4 + edge * 16 + c * 2 + 1);
        uint4 o;
        o.x = bf16rne(a.x) | (bf16rne(a.y) << 16);
        o.y = bf16rne(a.z) | (bf16rne(a.w) << 16);
        o.z = bf16rne(d.x) | (bf16rne(d.y) << 16);
        o.w = bf16rne(d.z) | (bf16rne(d.w) << 16);
        Es4[(size_t)pos * 8 + c] = o;
    }
}

// ---- Pass D: half-bucket segmented mean + amortized MLP ----
// 500 blocks: block d = bucket d>>1, half d&1 (nodes half*100 .. +100).
// LDS list per node from tags; 16 waves x 7 nodes; R12-proven mean + MLP.
__global__ __launch_bounds__(1024, 8) void passD_kernel(
    const unsigned* __restrict__ Es, const unsigned short* __restrict__ tags,
    const unsigned* __restrict__ bucketStart, const float* __restrict__ v,
    const float* __restrict__ W0, const float* __restrict__ b0,
    const float* __restrict__ W1, const float* __restrict__ b1,
    const float* __restrict__ W2, const float* __restrict__ b2,
    float* __restrict__ out)
{
    __shared__ float sW0[128 * 64];
    __shared__ float sW1[64 * 64];
    __shared__ float sW2[64 * 64];
    __shared__ float sB[3 * 64];
    __shared__ int cntL[NPH];
    __shared__ int startL[NPH];
    __shared__ int curL[NPH];
    __shared__ unsigned scanBuf[256];
    __shared__ unsigned short list[CAPD];

    const int tid = threadIdx.x;
    const int b = blockIdx.x >> 1;
    const int half = blockIdx.x & 1;

    for (int i = tid; i < 128 * 64; i += 1024) sW0[i] = W0[i];
    for (int i = tid; i < 64 * 64; i += 1024) sW1[i] = W1[i];
    for (int i = tid; i < 64 * 64; i += 1024) sW2[i] = W2[i];
    if (tid < 192) {
        sB[tid] = (tid < 64) ? b0[tid] : (tid < 128) ? b1[tid - 64] : b2[tid - 128];
    }
    if (tid < NPH) cntL[tid] = 0;
    __syncthreads();

    const int gbase = (int)bucketStart[b];
    int bcnt = (int)bucketStart[b + 1] - gbase;

    // histogram of this half's nodes over the bucket's rows
    for (int i = tid; i < bcnt; i += 1024) {
        int tg = tags[(size_t)gbase + i];
        if (tg / NPH == half) atomicAdd(&cntL[tg % NPH], 1);
    }
    __syncthreads();

    // exclusive scan over NPH counters (uniform barriers)
    unsigned vals = 0;
    if (tid < 256) { vals = (tid < NPH) ? (unsigned)cntL[tid] : 0u; scanBuf[tid] = vals; }
    __syncthreads();
    for (int off = 1; off < 256; off <<= 1) {
        unsigned vv = 0;
        if (tid < 256 && tid >= off) vv = scanBuf[tid - off];
        __syncthreads();
        if (tid < 256) scanBuf[tid] += vv;
        __syncthreads();
    }
    if (tid < NPH) { startL[tid] = (int)(scanBuf[tid] - vals); curL[tid] = (int)(scanBuf[tid] - vals); }
    __syncthreads();

    // fill per-node row lists (bucket-local row index, u16)
    for (int i = tid; i < bcnt; i += 1024) {
        int tg = tags[(size_t)gbase + i];
        if (tg / NPH == half) {
            int p = atomicAdd(&curL[tg % NPH], 1);
            if (p < CAPD) list[p] = (unsigned short)i;
        }
    }
    __syncthreads();

    const int lane = tid & 63;
    const int wid = tid >> 6;
    const int rg = lane >> 3;     // row-group 0..7
    const int ck = lane & 7;      // 16B chunk 0..7
    const uint4* Es4 = reinterpret_cast<const uint4*>(Es);

    float xa[NPW], xv[NPW];
    #pragma unroll
    for (int k = 0; k < NPW; ++k) {
        int ln = wid * NPW + k;            // wave-uniform
        xa[k] = 0.0f; xv[k] = 0.0f;
        if (ln < NPH) {
            int n = b * NPB + half * NPH + ln;
            xv[k] = v[(size_t)n * H + lane];
            int s0 = startL[ln];
            int c0 = cntL[ln];

            float f0 = 0.f, f1 = 0.f, f2 = 0.f, f3 = 0.f;
            float f4 = 0.f, f5 = 0.f, f6 = 0.f, f7 = 0.f;
            for (int p = 0; p < c0; p += 8) {
                int rr = p + rg;
                if (rr < c0) {
                    int idx = list[s0 + rr];
                    uint4 q = Es4[((size_t)gbase + idx) * 8 + ck];
                    f0 += bf16lo(q.x); f1 += bf16hi(q.x);
                    f2 += bf16lo(q.y); f3 += bf16hi(q.y);
                    f4 += bf16lo(q.z); f5 += bf16hi(q.z);
                    f6 += bf16lo(q.w); f7 += bf16hi(q.w);
                }
            }
            // reduce across 8 row-groups (lane bits 3,4,5)
            f0 += __shfl_xor(f0, 8);  f1 += __shfl_xor(f1, 8);
            f2 += __shfl_xor(f2, 8);  f3 += __shfl_xor(f3, 8);
            f4 += __shfl_xor(f4, 8);  f5 += __shfl_xor(f5, 8);
            f6 += __shfl_xor(f6, 8);  f7 += __shfl_xor(f7, 8);
            f0 += __shfl_xor(f0, 16); f1 += __shfl_xor(f1, 16);
            f2 += __shfl_xor(f2, 16); f3 += __shfl_xor(f3, 16);
            f4 += __shfl_xor(f4, 16); f5 += __shfl_xor(f5, 16);
            f6 += __shfl_xor(f6, 16); f7 += __shfl_xor(f7, 16);
            f0 += __shfl_xor(f0, 32); f1 += __shfl_xor(f1, 32);
            f2 += __shfl_xor(f2, 32); f3 += __shfl_xor(f3, 32);
            f4 += __shfl_xor(f4, 32); f5 += __shfl_xor(f5, 32);
            f6 += __shfl_xor(f6, 32); f7 += __shfl_xor(f7, 32);

            // redistribute: feature f=lane is slot f&7 of source lane f>>3
            int src = lane >> 3;
            float t0 = __shfl(f0, src), t1 = __shfl(f1, src);
            float t2 = __shfl(f2, src), t3 = __shfl(f3, src);
            float t4 = __shfl(f4, src), t5 = __shfl(f5, src);
            float t6 = __shfl(f6, src), t7 = __shfl(f7, src);
            float a01 = (lane & 1) ? t1 : t0;
            float a23 = (lane & 1) ? t3 : t2;
            float a45 = (lane & 1) ? t5 : t4;
            float a67 = (lane & 1) ? t7 : t6;
            float b03 = (lane & 2) ? a23 : a01;
            float b47 = (lane & 2) ? a67 : a45;
            float sel = (lane & 4) ? b47 : b03;

            float invc = (c0 > 0) ? 1.0f / (float)c0 : 0.0f;
            xa[k] = sel * invc;
        }
    }

    // ---- MLP: 1 LDS weight read per K-step, shared by 7 nodes ----
    float acc[NPW];
    #pragma unroll
    for (int k = 0; k < NPW; ++k) acc[k] = sB[lane];
    #pragma unroll 8
    for (int i = 0; i < 64; ++i) {
        float w = sW0[i * 64 + lane];
        #pragma unroll
        for (int k = 0; k < NPW; ++k) acc[k] = fmaf(readlane_f(xa[k], i), w, acc[k]);
    }
    #pragma unroll 8
    for (int i = 0; i < 64; ++i) {
        float w = sW0[(64 + i) * 64 + lane];
        #pragma unroll
        for (int k = 0; k < NPW; ++k) acc[k] = fmaf(readlane_f(xv[k], i), w, acc[k]);
    }
    float y[NPW];
    #pragma unroll
    for (int k = 0; k < NPW; ++k) y[k] = fmaxf(acc[k], 0.0f);

    #pragma unroll
    for (int k = 0; k < NPW; ++k) acc[k] = sB[64 + lane];
    #pragma unroll 8
    for (int i = 0; i < 64; ++i) {
        float w = sW1[i * 64 + lane];
        #pragma unroll
        for (int k = 0; k < NPW; ++k) acc[k] = fmaf(readlane_f(y[k], i), w, acc[k]);
    }
    float z[NPW];
    #pragma unroll
    for (int k = 0; k < NPW; ++k) z[k] = fmaxf(acc[k], 0.0f);

    #pragma unroll
    for (int k = 0; k < NPW; ++k) acc[k] = sB[128 + lane];
    #pragma unroll 8
    for (int i = 0; i < 64; ++i) {
        float w = sW2[i * 64 + lane];
        #pragma unroll
        for (int k = 0; k < NPW; ++k) acc[k] = fmaf(readlane_f(z[k], i), w, acc[k]);
    }

    #pragma unroll
    for (int k = 0; k < NPW; ++k) {
        int ln = wid * NPW + k;
        if (ln < NPH) {
            int n = b * NPB + half * NPH + ln;
            out[(size_t)n * H + lane] = acc[k];
        }
    }
}

extern "C" void kernel_launch(void* const* d_in, const int* in_sizes, int n_in,
                              void* d_out, int out_size, void* d_ws, size_t ws_size,
                              hipStream_t stream)
{
    const float* v  = (const float*)d_in[0];
    const int*   ei = (const int*)d_in[1];     // [2, 800000]; row 1 = receiver
    const float* e  = (const float*)d_in[2];
    const float* W0 = (const float*)d_in[3];
    const float* b0 = (const float*)d_in[4];
    const float* W1 = (const float*)d_in[5];
    const float* b1 = (const float*)d_in[6];
    const float* W2 = (const float*)d_in[7];
    const float* b2 = (const float*)d_in[8];
    float* out = (float*)d_out;

    // workspace layout (u32 units); every cell written before read -> no memset
    unsigned* W = (unsigned*)d_ws;
    unsigned*       histMatT    = W;                       // 250*250 = 62500 -> pad 62720
    unsigned*       offMatT     = W + 62720;               // 62500 -> pad 62720
    unsigned*       bucketTotal = W + 125440;              // 250 -> pad 256
    unsigned*       bucketStart = W + 125696;              // 251 -> pad 256
    unsigned short* tags        = (unsigned short*)(W + 125952);  // 800000 u16 = 400000 u32
    unsigned*       Es          = W + 525952;              // 800000 rows * 32 u32 (102.4 MB)
    const int* recv = ei + N_EDGES;

    histA_kernel<<<NB, 256, 0, stream>>>(recv, histMatT);
    scanB1_kernel<<<NB, 256, 0, stream>>>(histMatT, offMatT, bucketTotal);
    scanB2_kernel<<<1, 256, 0, stream>>>(bucketTotal, bucketStart);
    scatterC_kernel<<<NB, 1024, 0, stream>>>(e, recv, offMatT, bucketStart, tags, Es);
    passD_kernel<<<2 * NB, 1024, 0, stream>>>(
        Es, tags, bucketStart, v, W0, b0, W1, b1, W2, b2, out);
}